// Round 14
// baseline (526.411 us; speedup 1.0000x reference)
//
#include <hip/hip_runtime.h>
#include <hip/hip_bf16.h>
#include <math.h>

typedef __bf16 bf16_t;
typedef __bf16 bf16x8 __attribute__((ext_vector_type(8)));
typedef __bf16 bf16x4 __attribute__((ext_vector_type(4)));
typedef float f32x4 __attribute__((ext_vector_type(4)));

#define DIM 512
#define SCALE 0.04419417382415922f

static __device__ __forceinline__ bf16_t f2bf(float x) { return (bf16_t)x; }
static __device__ __forceinline__ int imin(int a, int b) { return a < b ? a : b; }

// async global->LDS, 16 B per lane (dest = wave-uniform base + lane*16)
static __device__ __forceinline__ void gload16(const void* g, void* l) {
    __builtin_amdgcn_global_load_lds((const __attribute__((address_space(1))) unsigned int*)g,
                                     (__attribute__((address_space(3))) unsigned int*)l,
                                     16, 0, 0);
}

// ---------------- f32 -> bf16 cast (both tensors, one dispatch) ----------------
__global__ __launch_bounds__(256) void cast2_bf16(const float* __restrict__ ina,
                                                  bf16_t* __restrict__ outa, int na8,
                                                  const float* __restrict__ inb,
                                                  bf16_t* __restrict__ outb, int nb8)
{
    int i = blockIdx.x * 256 + threadIdx.x;
    const float* p;
    bf16_t* o;
    if (i < na8) {
        p = ina + (size_t)i * 8;  o = outa + (size_t)i * 8;
    } else {
        i -= na8;
        if (i >= nb8) return;
        p = inb + (size_t)i * 8;  o = outb + (size_t)i * 8;
    }
    f32x4 a = *(const f32x4*)(p);
    f32x4 b = *(const f32x4*)(p + 4);
    bf16x8 v;
    #pragma unroll
    for (int u = 0; u < 4; ++u) { v[u] = f2bf(a[u]); v[4 + u] = f2bf(b[u]); }
    *(bf16x8*)o = v;
}

// ---------------- weight transpose+cast: Wt[z][n][k] = W_z[k][n] ----------------
__global__ void wt_kernel(const float* __restrict__ W0, const float* __restrict__ W1,
                          const float* __restrict__ W2, const float* __restrict__ W3,
                          const float* __restrict__ W4, const float* __restrict__ W5,
                          bf16_t* __restrict__ Wt)
{
    __shared__ float tile[32][33];
    const float* W;
    switch (blockIdx.z) {
        case 0: W = W0; break; case 1: W = W1; break; case 2: W = W2; break;
        case 3: W = W3; break; case 4: W = W4; break; default: W = W5; break;
    }
    const int tx = threadIdx.x, ty = threadIdx.y;
    const int n0 = blockIdx.x * 32, k0 = blockIdx.y * 32;
    #pragma unroll
    for (int r = 0; r < 4; ++r)
        tile[ty + 8*r][tx] = W[(size_t)(k0 + ty + 8*r) * DIM + n0 + tx];
    __syncthreads();
    bf16_t* Wtz = Wt + (size_t)blockIdx.z * DIM * DIM;
    #pragma unroll
    for (int r = 0; r < 4; ++r)
        Wtz[(size_t)(n0 + ty + 8*r) * DIM + k0 + tx] = f2bf(tile[tx][ty + 8*r]);
}

// ---------------- fused QKV projection GEMM — BARRIER-FREE K-loop -------------
// Each wave owns a private 64x64 output tile AND private LDS A/W buffers
// (64x32 each, double-buffered). vmcnt is per-wave, so s_waitcnt vmcnt(8)
// alone proves tile-kk residency — no s_barrier in the loop. WAR on buffer
// reuse: lgkmcnt(0)+sched_barrier before the stage ensures this wave's
// ds_reads of that buffer retired before the overwriting loads issue.
// Blocks [0,7200): eeg side. [7200,8640): fnirs side.
__global__ __launch_bounds__(256, 2)
void proj_both(const bf16_t* __restrict__ Ae, const bf16_t* __restrict__ Af,
               const bf16_t* __restrict__ WtBase,
               const float* __restrict__ bqe, const float* __restrict__ bke, const float* __restrict__ bve,
               const float* __restrict__ bqf, const float* __restrict__ bkf, const float* __restrict__ bvf,
               bf16_t* __restrict__ Qe, bf16_t* __restrict__ Ke, bf16_t* __restrict__ VeT,
               bf16_t* __restrict__ Qf, bf16_t* __restrict__ Kf, bf16_t* __restrict__ VfT)
{
    __shared__ __align__(16) bf16_t smem[4][2][2][2048];   // [wave][buf][0=A,1=W][64x32]

    int g = blockIdx.x;
    const bf16_t* A; const bf16_t* Wt;
    const float *bq, *bk, *bv;
    bf16_t *Q, *K, *Vt;
    int TT, TKP;
    if (g < 7200) {
        A = Ae;  Wt = WtBase;
        bq = bqe; bk = bke; bv = bve;
        Q = Qe; K = Ke; Vt = VeT;
        TT = 600; TKP = 608;
    } else {
        g -= 7200;
        A = Af;  Wt = WtBase + 3 * 262144;
        bq = bqf; bk = bkf; bv = bvf;
        Q = Qf; K = Kf; Vt = VfT;
        TT = 120; TKP = 128;
    }

    const int x = g & 7, t = g >> 3;
    const int colt = t % 12;
    const int rowt = (t / 12) * 8 + x;
    const int tid = threadIdx.x;
    const int wv = tid >> 6, lane = tid & 63, l15 = lane & 15, l4 = lane >> 4;
    const int mBase = rowt * 128, nBase = colt * 128;
    const int wr = wv >> 1, wc = wv & 1;

    // per-wave staging: 4 chunks x (16 rows x 32 cols); r = c*16 + (lane>>2),
    // slot = lane&3 (16 B); source slot pre-swizzled: slot ^ ((r>>1)&3)
    const bf16_t* aP[4];
    const bf16_t* wP[4];
    #pragma unroll
    for (int c = 0; c < 4; ++c) {
        const int r = c * 16 + (lane >> 2);
        const int s = (lane & 3) ^ ((r >> 1) & 3);
        aP[c] = A  + (size_t)(mBase + wr * 64 + r) * DIM + s * 8;
        wP[c] = Wt + (size_t)(nBase + wc * 64 + r) * DIM + s * 8;
    }

    auto stage = [&](int B, int KK) {   // 8 gload16 per lane (A 4 + W 4)
        #pragma unroll
        for (int c = 0; c < 4; ++c)
            gload16(aP[c] + KK * 32, &smem[wv][B][0][c * 512 + lane * 8]);
        #pragma unroll
        for (int c = 0; c < 4; ++c)
            gload16(wP[c] + KK * 32, &smem[wv][B][1][c * 512 + lane * 8]);
    };

    f32x4 acc[4][4];
    #pragma unroll
    for (int f = 0; f < 4; ++f)
        #pragma unroll
        for (int gg = 0; gg < 4; ++gg) acc[f][gg] = (f32x4){0.f, 0.f, 0.f, 0.f};

    stage(0, 0);
    stage(1, 1);                       // 16 loads/lane in flight

    #pragma unroll
    for (int kk = 0; kk < 16; ++kk) {
        // tile kk resident: outstanding = tiles kk,kk+1 (16); vmcnt(8) retires kk
        if (kk < 15) asm volatile("s_waitcnt vmcnt(8)" ::: "memory");
        else         asm volatile("s_waitcnt vmcnt(0)" ::: "memory");
        __builtin_amdgcn_sched_barrier(0);

        const int cb = kk & 1;
        bf16x8 af[4], bfr[4];
        #pragma unroll
        for (int f = 0; f < 4; ++f) {
            const int r = f * 16 + l15;
            af[f] = *(const bf16x8*)&smem[wv][cb][0][r * 32 + (l4 ^ ((r >> 1) & 3)) * 8];
        }
        #pragma unroll
        for (int gg = 0; gg < 4; ++gg) {
            const int r = gg * 16 + l15;
            bfr[gg] = *(const bf16x8*)&smem[wv][cb][1][r * 32 + (l4 ^ ((r >> 1) & 3)) * 8];
        }
        #pragma unroll
        for (int f = 0; f < 4; ++f)
            #pragma unroll
            for (int gg = 0; gg < 4; ++gg)
                acc[f][gg] = __builtin_amdgcn_mfma_f32_16x16x32_bf16(af[f], bfr[gg], acc[f][gg], 0, 0, 0);

        // all ds_reads of buf cb retired before we overwrite it (per-wave WAR)
        asm volatile("s_waitcnt lgkmcnt(0)" ::: "memory");
        __builtin_amdgcn_sched_barrier(0);
        if (kk < 14) stage(cb, kk + 2);
    }
    __syncthreads();                    // waves rendezvous once, before overlay

    // ---------------- transposed epilogue through LDS ----------------
    bf16_t* cst = &smem[0][0][0][0];            // 128x128 bf16 overlay (32 KB)
    const int sel = colt >> 2;                  // 0=Q, 1=K, 2=V
    const int nb  = nBase - sel * 512;
    const float* bp = (sel == 0) ? bq : ((sel == 1) ? bk : bv);

    if (sel < 2) {
        #pragma unroll
        for (int gg = 0; gg < 4; ++gg) {
            const int ncol = wc * 64 + gg * 16 + l15;
            const float bias_v = bp[nb + ncol];
            #pragma unroll
            for (int f = 0; f < 4; ++f)
                #pragma unroll
                for (int i = 0; i < 4; ++i)
                    cst[(wr * 64 + f * 16 + 4 * l4 + i) * 128 + ncol] = f2bf(acc[f][gg][i] + bias_v);
        }
        __syncthreads();
        bf16_t* Cout = (sel == 0) ? Q : K;
        #pragma unroll
        for (int rr = 0; rr < 4; ++rr) {
            const int r  = rr * 32 + (tid >> 3);
            const int c0 = (tid & 7) * 16;
            bf16x8 v0 = *(const bf16x8*)&cst[r * 128 + c0];
            bf16x8 v1 = *(const bf16x8*)&cst[r * 128 + c0 + 8];
            bf16_t* dst = Cout + (size_t)(mBase + r) * DIM + nb + c0;
            *(bf16x8*)dst       = v0;
            *(bf16x8*)(dst + 8) = v1;
        }
    } else {
        #pragma unroll
        for (int gg = 0; gg < 4; ++gg) {
            const int ncol = wc * 64 + gg * 16 + l15;
            const float bias_v = bp[nb + ncol];
            #pragma unroll
            for (int f = 0; f < 4; ++f) {
                bf16x4 pk;
                #pragma unroll
                for (int i = 0; i < 4; ++i) pk[i] = f2bf(acc[f][gg][i] + bias_v);
                *(bf16x4*)&cst[ncol * 128 + wr * 64 + f * 16 + 4 * l4] = pk;
            }
        }
        __syncthreads();
        #pragma unroll
        for (int rr = 0; rr < 4; ++rr) {
            const int nl = rr * 32 + (tid >> 3);
            const int m0 = (tid & 7) * 16;
            const int n  = nb + nl;
            const int mg0 = mBase + m0;
            const int bb0 = mg0 / TT, tt0 = mg0 - bb0 * TT;
            if (tt0 + 15 < TT) {
                bf16_t* dst = Vt + (size_t)bb0 * DIM * TKP + (size_t)n * TKP + tt0;
                #pragma unroll
                for (int u = 0; u < 4; ++u)
                    *(bf16x4*)(dst + u * 4) = *(const bf16x4*)&cst[nl * 128 + m0 + u * 4];
            } else {
                #pragma unroll
                for (int u = 0; u < 16; ++u) {
                    const int mg = mg0 + u;
                    const int bb = mg / TT, tt = mg - bb * TT;
                    Vt[(size_t)bb * DIM * TKP + (size_t)n * TKP + tt] = cst[nl * 128 + m0 + u];
                }
            }
        }
    }
}

// ---------------- merged attention: f2e blocks [0,512), e2f blocks [512,1152) --
__global__ __launch_bounds__(256, 3)
void attn_both(const bf16_t* __restrict__ Qe, const bf16_t* __restrict__ Kf,
               const bf16_t* __restrict__ VfT, float* __restrict__ OutF,
               const bf16_t* __restrict__ Qf, const bf16_t* __restrict__ Ke,
               const bf16_t* __restrict__ VeT, float* __restrict__ OutE)
{
    __shared__ __align__(16) char smem_raw[43520];

    const int gid = blockIdx.x;
    const int tid = threadIdx.x;
    const int wv = tid >> 6, lane = tid & 63, l15 = lane & 15, l4 = lane >> 4;

    if (gid < 512) {
        // ================= f2e: Q=fnirs 120 rows, K/V=eeg 600 keys =================
        bf16_t (*p_lds)[648] = (bf16_t(*)[648])smem_raw;
        float (*m_lds)[32]   = (float(*)[32])(smem_raw + 41472);
        float (*l_lds)[32]   = (float(*)[32])(smem_raw + 41984);

        const int b = gid & 127, qt = gid >> 7;
        const int qbase0 = qt * 32;
        const int koff = wv * 160;

        const bf16_t* Qb = Qf + (size_t)b * 120 * DIM;
        const bf16_t* Kb = Ke + (size_t)b * 600 * DIM;
        const bf16_t* Vb = VeT + (size_t)b * DIM * 608;

        const int qr0 = imin(qbase0 + l15, 119);
        const int qr1 = imin(qbase0 + 16 + l15, 119);
        const bf16_t* qp0 = Qb + (size_t)qr0 * DIM + l4 * 8;
        const bf16_t* qp1 = Qb + (size_t)qr1 * DIM + l4 * 8;

        int koffs[10];
        #pragma unroll
        for (int ch = 0; ch < 10; ++ch)
            koffs[ch] = imin(koff + ch * 16 + l15, 599) * (DIM * 2);
        const char* KbL = (const char*)(Kb + l4 * 8);

        f32x4 acc0[10], acc1[10];
        #pragma unroll
        for (int ch = 0; ch < 10; ++ch) { acc0[ch] = (f32x4){0.f,0.f,0.f,0.f};
                                          acc1[ch] = (f32x4){0.f,0.f,0.f,0.f}; }
        #pragma unroll 2
        for (int c = 0; c < 16; ++c) {
            bf16x8 q0c = *(const bf16x8*)(qp0 + c * 32);
            bf16x8 q1c = *(const bf16x8*)(qp1 + c * 32);
            #pragma unroll
            for (int ch = 0; ch < 10; ++ch) {
                bf16x8 kf = *(const bf16x8*)(KbL + koffs[ch] + c * 64);
                acc0[ch] = __builtin_amdgcn_mfma_f32_16x16x32_bf16(q0c, kf, acc0[ch], 0, 0, 0);
                acc1[ch] = __builtin_amdgcn_mfma_f32_16x16x32_bf16(q1c, kf, acc1[ch], 0, 0, 0);
            }
        }

        float m0[4] = {-INFINITY,-INFINITY,-INFINITY,-INFINITY};
        float m1[4] = {-INFINITY,-INFINITY,-INFINITY,-INFINITY};
        #pragma unroll
        for (int ch = 0; ch < 10; ++ch) {
            #pragma unroll
            for (int i = 0; i < 4; ++i) {
                const int k = koff + ch * 16 + l15;
                const int j0 = k / 20;
                {   const int j = qbase0 + 4 * l4 + i;
                    float s = (k >= 600) ? -INFINITY
                            : ((j >= j0 + 20 && j <= j0 + 80) ? acc0[ch][i] * SCALE : -1e9f);
                    acc0[ch][i] = s;  m0[i] = fmaxf(m0[i], s); }
                {   const int j = qbase0 + 16 + 4 * l4 + i;
                    float s = (k >= 600) ? -INFINITY
                            : ((j >= j0 + 20 && j <= j0 + 80) ? acc1[ch][i] * SCALE : -1e9f);
                    acc1[ch][i] = s;  m1[i] = fmaxf(m1[i], s); }
            }
        }
        #pragma unroll
        for (int i = 0; i < 4; ++i) {
            #pragma unroll
            for (int d = 1; d < 16; d <<= 1) {
                m0[i] = fmaxf(m0[i], __shfl_xor(m0[i], d, 16));
                m1[i] = fmaxf(m1[i], __shfl_xor(m1[i], d, 16));
            }
        }
        if (l15 == 0) {
            #pragma unroll
            for (int i = 0; i < 4; ++i) {
                m_lds[wv][4 * l4 + i]      = m0[i];
                m_lds[wv][16 + 4 * l4 + i] = m1[i];
            }
        }
        __syncthreads();
        float mg0[4], mg1[4];
        #pragma unroll
        for (int i = 0; i < 4; ++i) {
            const int r0 = 4 * l4 + i, r1 = 16 + 4 * l4 + i;
            mg0[i] = fmaxf(fmaxf(m_lds[0][r0], m_lds[1][r0]), fmaxf(m_lds[2][r0], m_lds[3][r0]));
            mg1[i] = fmaxf(fmaxf(m_lds[0][r1], m_lds[1][r1]), fmaxf(m_lds[2][r1], m_lds[3][r1]));
        }

        float l0[4] = {0.f,0.f,0.f,0.f}, l1[4] = {0.f,0.f,0.f,0.f};
        #pragma unroll
        for (int ch = 0; ch < 10; ++ch) {
            #pragma unroll
            for (int i = 0; i < 4; ++i) {
                float e0 = __expf(acc0[ch][i] - mg0[i]);
                float e1 = __expf(acc1[ch][i] - mg1[i]);
                l0[i] += e0;  l1[i] += e1;
                p_lds[4 * l4 + i][koff + ch * 16 + l15]      = f2bf(e0);
                p_lds[16 + 4 * l4 + i][koff + ch * 16 + l15] = f2bf(e1);
            }
        }
        #pragma unroll
        for (int i = 0; i < 4; ++i) {
            #pragma unroll
            for (int d = 1; d < 16; d <<= 1) {
                l0[i] += __shfl_xor(l0[i], d, 16);
                l1[i] += __shfl_xor(l1[i], d, 16);
            }
        }
        if (l15 == 0) {
            #pragma unroll
            for (int i = 0; i < 4; ++i) {
                l_lds[wv][4 * l4 + i]      = l0[i];
                l_lds[wv][16 + 4 * l4 + i] = l1[i];
            }
        }
        __syncthreads();   // P + l published

        float linv0[4], linv1[4];
        #pragma unroll
        for (int i = 0; i < 4; ++i) {
            const int r0 = 4 * l4 + i, r1 = 16 + 4 * l4 + i;
            linv0[i] = 1.0f / (l_lds[0][r0] + l_lds[1][r0] + l_lds[2][r0] + l_lds[3][r0]);
            linv1[i] = 1.0f / (l_lds[0][r1] + l_lds[1][r1] + l_lds[2][r1] + l_lds[3][r1]);
        }

        const int dbase = wv * 128;
        f32x4 o0[8], o1[8];
        #pragma unroll
        for (int u = 0; u < 8; ++u) { o0[u] = (f32x4){0.f,0.f,0.f,0.f};
                                      o1[u] = (f32x4){0.f,0.f,0.f,0.f}; }

        for (int kt = 0; kt < 20; ++kt) {
            bf16x8 pa0 = *(const bf16x8*)&p_lds[l15][kt * 32 + l4 * 8];
            bf16x8 pa1 = *(const bf16x8*)&p_lds[16 + l15][kt * 32 + l4 * 8];
            const int vcol = imin(kt * 32, 576);
            #pragma unroll
            for (int u = 0; u < 8; ++u) {
                bf16x8 vf = *(const bf16x8*)(Vb + (size_t)(dbase + u * 16 + l15) * 608 + vcol + l4 * 8);
                o0[u] = __builtin_amdgcn_mfma_f32_16x16x32_bf16(pa0, vf, o0[u], 0, 0, 0);
                o1[u] = __builtin_amdgcn_mfma_f32_16x16x32_bf16(pa1, vf, o1[u], 0, 0, 0);
            }
        }

        float* Ob = OutE + (size_t)b * 120 * DIM;
        #pragma unroll
        for (int u = 0; u < 8; ++u) {
            #pragma unroll
            for (int i = 0; i < 4; ++i) {
                const int col = dbase + u * 16 + l15;
                const int r0 = qbase0 + 4 * l4 + i;
                const int r1 = qbase0 + 16 + 4 * l4 + i;
                if (r0 < 120) Ob[(size_t)r0 * DIM + col] = o0[u][i] * linv0[i];
                if (r1 < 120) Ob[(size_t)r1 * DIM + col] = o1[u][i] * linv1[i];
            }
        }
    } else {
        // ================= e2f: Q=eeg 600 rows, K/V=fnirs 120 keys =================
        bf16_t (*p_lds)[32][104] = (bf16_t(*)[32][104])smem_raw;

        const int g2 = gid - 512;
        const int b = g2 & 127, qb = g2 >> 7;
        const int qbase = qb * 128 + wv * 32;
        const int K0 = (((qbase / 20) + 20) >> 4) << 4;      // <= 48

        const bf16_t* Qb = Qe + (size_t)b * 600 * DIM;
        const bf16_t* Kb = Kf + (size_t)b * 120 * DIM;
        const bf16_t* Vb = VfT + (size_t)b * DIM * 128;

        const int qr0 = imin(qbase + l15, 599);
        const int qr1 = imin(qbase + 16 + l15, 599);
        const bf16_t* qp0 = Qb + (size_t)qr0 * DIM + l4 * 8;
        const bf16_t* qp1 = Qb + (size_t)qr1 * DIM + l4 * 8;

        int koffs[6];
        #pragma unroll
        for (int ch = 0; ch < 6; ++ch)
            koffs[ch] = imin(K0 + ch * 16 + l15, 119) * (DIM * 2);
        const char* KbL = (const char*)(Kb + l4 * 8);

        f32x4 acc0[6], acc1[6];
        #pragma unroll
        for (int ch = 0; ch < 6; ++ch) { acc0[ch] = (f32x4){0.f,0.f,0.f,0.f};
                                         acc1[ch] = (f32x4){0.f,0.f,0.f,0.f}; }
        #pragma unroll
        for (int c = 0; c < 16; ++c) {
            bf16x8 q0c = *(const bf16x8*)(qp0 + c * 32);
            bf16x8 q1c = *(const bf16x8*)(qp1 + c * 32);
            #pragma unroll
            for (int ch = 0; ch < 6; ++ch) {
                bf16x8 kf = *(const bf16x8*)(KbL + koffs[ch] + c * 64);
                acc0[ch] = __builtin_amdgcn_mfma_f32_16x16x32_bf16(q0c, kf, acc0[ch], 0, 0, 0);
                acc1[ch] = __builtin_amdgcn_mfma_f32_16x16x32_bf16(q1c, kf, acc1[ch], 0, 0, 0);
            }
        }

        float m0[4] = {-INFINITY,-INFINITY,-INFINITY,-INFINITY};
        float m1[4] = {-INFINITY,-INFINITY,-INFINITY,-INFINITY};
        #pragma unroll
        for (int ch = 0; ch < 6; ++ch) {
            #pragma unroll
            for (int i = 0; i < 4; ++i) {
                const int k = K0 + ch * 16 + l15;
                {   const int t = qbase + 4 * l4 + i;
                    const int j0 = t / 20;
                    const bool v = (k < 120) && (k >= j0 + 20) && (k <= j0 + 80);
                    float s = v ? acc0[ch][i] * SCALE : -INFINITY;
                    acc0[ch][i] = s;  m0[i] = fmaxf(m0[i], s); }
                {   const int t = qbase + 16 + 4 * l4 + i;
                    const int j0 = t / 20;
                    const bool v = (k < 120) && (k >= j0 + 20) && (k <= j0 + 80);
                    float s = v ? acc1[ch][i] * SCALE : -INFINITY;
                    acc1[ch][i] = s;  m1[i] = fmaxf(m1[i], s); }
            }
        }
        #pragma unroll
        for (int i = 0; i < 4; ++i) {
            #pragma unroll
            for (int d = 1; d < 16; d <<= 1) {
                m0[i] = fmaxf(m0[i], __shfl_xor(m0[i], d, 16));
                m1[i] = fmaxf(m1[i], __shfl_xor(m1[i], d, 16));
            }
        }

        float l0[4] = {0.f,0.f,0.f,0.f}, l1[4] = {0.f,0.f,0.f,0.f};
        #pragma unroll
        for (int ch = 0; ch < 6; ++ch) {
            #pragma unroll
            for (int i = 0; i < 4; ++i) {
                float e0 = __expf(acc0[ch][i] - m0[i]);
                float e1 = __expf(acc1[ch][i] - m1[i]);
                l0[i] += e0;  l1[i] += e1;
                p_lds[wv][4 * l4 + i][ch * 16 + l15]      = f2bf(e0);
                p_lds[wv][16 + 4 * l4 + i][ch * 16 + l15] = f2bf(e1);
            }
        }
        #pragma unroll
        for (int i = 0; i < 4; ++i) {
            #pragma unroll
            for (int d = 1; d < 16; d <<= 1) {
                l0[i] += __shfl_xor(l0[i], d, 16);
                l1[i] += __shfl_xor(l1[i], d, 16);
            }
            l0[i] = 1.0f / l0[i];
            l1[i] = 1.0f / l1[i];
        }
        __syncthreads();   // fence p_lds write -> read

        bf16x8 pa0[3], pa1[3];
        #pragma unroll
        for (int kt = 0; kt < 3; ++kt) {
            pa0[kt] = *(const bf16x8*)&p_lds[wv][l15][kt * 32 + l4 * 8];
            pa1[kt] = *(const bf16x8*)&p_lds[wv][16 + l15][kt * 32 + l4 * 8];
        }
        int vb[3];
        #pragma unroll
        for (int kt = 0; kt < 3; ++kt) vb[kt] = imin(K0 + kt * 32, 96);  // P==0 where clamped

        float* Ob = OutF + (size_t)b * 600 * DIM;
        #pragma unroll
        for (int dcg = 0; dcg < 8; ++dcg) {
            f32x4 o0[4], o1[4];
            #pragma unroll
            for (int u = 0; u < 4; ++u) { o0[u] = (f32x4){0.f,0.f,0.f,0.f};
                                          o1[u] = (f32x4){0.f,0.f,0.f,0.f}; }
            #pragma unroll
            for (int u = 0; u < 4; ++u) {
                const bf16_t* vrow = Vb + (size_t)(dcg * 64 + u * 16 + l15) * 128 + l4 * 8;
                #pragma unroll
                for (int kt = 0; kt < 3; ++kt) {
                    bf16x8 vf = *(const bf16x8*)(vrow + vb[kt]);
                    o0[u] = __builtin_amdgcn_mfma_f32_16x16x32_bf16(pa0[kt], vf, o0[u], 0, 0, 0);
                    o1[u] = __builtin_amdgcn_mfma_f32_16x16x32_bf16(pa1[kt], vf, o1[u], 0, 0, 0);
                }
            }
            #pragma unroll
            for (int u = 0; u < 4; ++u) {
                #pragma unroll
                for (int i = 0; i < 4; ++i) {
                    const int col = (dcg * 4 + u) * 16 + l15;
                    const int t0 = qbase + 4 * l4 + i;
                    const int t1 = qbase + 16 + 4 * l4 + i;
                    if (t0 < 600) Ob[(size_t)t0 * DIM + col] = o0[u][i] * l0[i];
                    if (t1 < 600) Ob[(size_t)t1 * DIM + col] = o1[u][i] * l1[i];
                }
            }
        }
    }
}

// ---------------- host launch ----------------
extern "C" void kernel_launch(void* const* d_in, const int* in_sizes, int n_in,
                              void* d_out, int out_size, void* d_ws, size_t ws_size,
                              hipStream_t stream)
{
    (void)in_sizes; (void)n_in; (void)out_size; (void)ws_size;
    const float* eeg   = (const float*)d_in[0];
    const float* fnirs = (const float*)d_in[1];
    const float* Wqe = (const float*)d_in[2];  const float* bqe = (const float*)d_in[3];
    const float* Wke = (const float*)d_in[4];  const float* bke = (const float*)d_in[5];
    const float* Wve = (const float*)d_in[6];  const float* bve = (const float*)d_in[7];
    const float* Wqf = (const float*)d_in[8];  const float* bqf = (const float*)d_in[9];
    const float* Wkf = (const float*)d_in[10]; const float* bkf = (const float*)d_in[11];
    const float* Wvf = (const float*)d_in[12]; const float* bvf = (const float*)d_in[13];

    char* ws = (char*)d_ws;
    bf16_t* Wt   = (bf16_t*)(ws);                      // 3,145,728 B
    bf16_t* Qe   = (bf16_t*)(ws + 3145728);            // 78,643,200
    bf16_t* Ke   = (bf16_t*)(ws + 81788928);           // 78,643,200
    bf16_t* Qf   = (bf16_t*)(ws + 160432128);          // 15,728,640
    bf16_t* Kf   = (bf16_t*)(ws + 176160768);          // 15,728,640
    bf16_t* Ve_t = (bf16_t*)(ws + 191889408);          // 79,691,776
    bf16_t* Vf_t = (bf16_t*)(ws + 271581184);          // 16,777,216  (total 288,358,400)

    float* out_eeg   = (float*)d_out;                              // [128][120][512]
    float* out_fnirs = (float*)d_out + (size_t)128 * 120 * 512;    // [128][600][512]

    // bf16 copies of the activations, parked in d_out (fully overwritten by attn later)
    bf16_t* eeg_bf   = (bf16_t*)out_fnirs;     // 78.6 MB <= 157 MB region
    bf16_t* fnirs_bf = (bf16_t*)out_eeg;       // 15.7 MB <= 31.5 MB region

    const int n8_e = 128 * 600 * DIM / 8;      // 4,915,200
    const int n8_f = 128 * 120 * DIM / 8;      // 983,040
    cast2_bf16<<<(n8_e + n8_f + 255) / 256, 256, 0, stream>>>(eeg, eeg_bf, n8_e,
                                                              fnirs, fnirs_bf, n8_f);

    // Wt rows: [Wqe^T; Wke^T; Wve^T; Wqf^T; Wkf^T; Wvf^T]
    wt_kernel<<<dim3(16, 16, 6), dim3(32, 8), 0, stream>>>(Wqe, Wke, Wve, Wqf, Wkf, Wvf, Wt);

    // fused QKV projections, both sides in one dispatch (7200 eeg + 1440 fnirs)
    proj_both<<<8640, 256, 0, stream>>>(eeg_bf, fnirs_bf, Wt,
                                        bqe, bke, bve, bqf, bkf, bvf,
                                        Qe, Ke, Ve_t, Qf, Kf, Vf_t);

    // both attentions in one dispatch (512 f2e + 640 e2f)
    attn_both<<<1152, 256, 0, stream>>>(Qe, Kf, Vf_t, out_fnirs,
                                        Qf, Ke, Ve_t, out_eeg);
}

// Round 15
// 464.218 us; speedup vs baseline: 1.1340x; 1.1340x over previous
//
#include <hip/hip_runtime.h>
#include <hip/hip_bf16.h>
#include <math.h>

typedef __bf16 bf16_t;
typedef __bf16 bf16x8 __attribute__((ext_vector_type(8)));
typedef __bf16 bf16x4 __attribute__((ext_vector_type(4)));
typedef float f32x4 __attribute__((ext_vector_type(4)));

#define DIM 512
#define SCALE 0.04419417382415922f

static __device__ __forceinline__ bf16_t f2bf(float x) { return (bf16_t)x; }
static __device__ __forceinline__ int imin(int a, int b) { return a < b ? a : b; }

// async global->LDS, 16 B per lane (dest = wave-uniform base + lane*16)
static __device__ __forceinline__ void gload16(const void* g, void* l) {
    __builtin_amdgcn_global_load_lds((const __attribute__((address_space(1))) unsigned int*)g,
                                     (__attribute__((address_space(3))) unsigned int*)l,
                                     16, 0, 0);
}

// ---------------- cast (f32->bf16, both tensors) + weight transpose, one dispatch
// Blocks [0,nCast): vectorized cast. Blocks [nCast, nCast+1536): Wt[z][n][k]=W_z[k][n].
__global__ __launch_bounds__(256)
void cast_wt(const float* __restrict__ ina, bf16_t* __restrict__ outa, int na8,
             const float* __restrict__ inb, bf16_t* __restrict__ outb, int nb8, int nCast,
             const float* __restrict__ W0, const float* __restrict__ W1,
             const float* __restrict__ W2, const float* __restrict__ W3,
             const float* __restrict__ W4, const float* __restrict__ W5,
             bf16_t* __restrict__ Wt)
{
    __shared__ float tile[32][33];
    const int bid = blockIdx.x;
    const int tid = threadIdx.x;

    if (bid < nCast) {
        int i = bid * 256 + tid;
        const float* p;
        bf16_t* o;
        if (i < na8) {
            p = ina + (size_t)i * 8;  o = outa + (size_t)i * 8;
        } else {
            i -= na8;
            if (i >= nb8) return;
            p = inb + (size_t)i * 8;  o = outb + (size_t)i * 8;
        }
        f32x4 a = *(const f32x4*)(p);
        f32x4 b = *(const f32x4*)(p + 4);
        bf16x8 v;
        #pragma unroll
        for (int u = 0; u < 4; ++u) { v[u] = f2bf(a[u]); v[4 + u] = f2bf(b[u]); }
        *(bf16x8*)o = v;
        return;
    }

    // weight-transpose path (block-uniform branch)
    const int g = bid - nCast;               // [0,1536)
    const int z = g >> 8;                    // 6 weights
    const int rem = g & 255;
    const int n0 = (rem & 15) * 32, k0 = (rem >> 4) * 32;
    const float* W;
    switch (z) {
        case 0: W = W0; break; case 1: W = W1; break; case 2: W = W2; break;
        case 3: W = W3; break; case 4: W = W4; break; default: W = W5; break;
    }
    const int tx = tid & 31, ty = tid >> 5;  // 32 x 8
    #pragma unroll
    for (int r = 0; r < 4; ++r)
        tile[ty + 8*r][tx] = W[(size_t)(k0 + ty + 8*r) * DIM + n0 + tx];
    __syncthreads();
    bf16_t* Wtz = Wt + (size_t)z * DIM * DIM;
    #pragma unroll
    for (int r = 0; r < 4; ++r)
        Wtz[(size_t)(n0 + ty + 8*r) * DIM + k0 + tx] = f2bf(tile[tx][ty + 8*r]);
}

// ---------------- fused QKV projection GEMM, BOTH sides in one dispatch --------
// Blocks [0,7200): eeg side (TT=600,TKP=608). Blocks [7200,8640): fnirs side.
// r7 structure: triple-buffered LDS, depth-2 prefetch, counted vmcnt,
// stage-after-barrier. TT/TKP are runtime (epilogue-only use).
__global__ __launch_bounds__(256, 3)
void proj_both(const bf16_t* __restrict__ Ae, const bf16_t* __restrict__ Af,
               const bf16_t* __restrict__ WtBase,
               const float* __restrict__ bqe, const float* __restrict__ bke, const float* __restrict__ bve,
               const float* __restrict__ bqf, const float* __restrict__ bkf, const float* __restrict__ bvf,
               bf16_t* __restrict__ Qe, bf16_t* __restrict__ Ke, bf16_t* __restrict__ VeT,
               bf16_t* __restrict__ Qf, bf16_t* __restrict__ Kf, bf16_t* __restrict__ VfT)
{
    __shared__ __align__(16) bf16_t smem[3][2][4096];   // [buf][0=A,1=W][128x32]

    int g = blockIdx.x;
    const bf16_t* A; const bf16_t* Wt;
    const float *bq, *bk, *bv;
    bf16_t *Q, *K, *Vt;
    int TT, TKP;
    if (g < 7200) {
        A = Ae;  Wt = WtBase;
        bq = bqe; bk = bke; bv = bve;
        Q = Qe; K = Ke; Vt = VeT;
        TT = 600; TKP = 608;
    } else {
        g -= 7200;
        A = Af;  Wt = WtBase + 3 * 262144;
        bq = bqf; bk = bkf; bv = bvf;
        Q = Qf; K = Kf; Vt = VfT;
        TT = 120; TKP = 128;
    }

    const int x = g & 7, t = g >> 3;
    const int colt = t % 12;
    const int rowt = (t / 12) * 8 + x;
    const int tid = threadIdx.x;
    const int wv = tid >> 6, lane = tid & 63, l15 = lane & 15, l4 = lane >> 4;
    const int mBase = rowt * 128, nBase = colt * 128;
    const int wr = wv >> 1, wc = wv & 1;

    const bf16_t* aP[2];
    const bf16_t* wP[2];
    #pragma unroll
    for (int c = 0; c < 2; ++c) {
        const int r = c * 64 + (tid >> 2);
        const int s = (tid & 3) ^ ((r >> 1) & 3);
        aP[c] = A  + (size_t)(mBase + r) * DIM + s * 8;
        wP[c] = Wt + (size_t)(nBase + r) * DIM + s * 8;
    }

    auto stage = [&](int B, int KK) {
        #pragma unroll
        for (int c = 0; c < 2; ++c)
            gload16(aP[c] + KK * 32, &smem[B][0][c * 2048 + tid * 8]);
        #pragma unroll
        for (int c = 0; c < 2; ++c)
            gload16(wP[c] + KK * 32, &smem[B][1][c * 2048 + tid * 8]);
    };

    f32x4 acc[4][4];
    #pragma unroll
    for (int f = 0; f < 4; ++f)
        #pragma unroll
        for (int gg = 0; gg < 4; ++gg) acc[f][gg] = (f32x4){0.f, 0.f, 0.f, 0.f};

    stage(0, 0);
    stage(1, 1);

    #pragma unroll
    for (int kk = 0; kk < 16; ++kk) {
        if (kk < 15) asm volatile("s_waitcnt vmcnt(4)" ::: "memory");
        else         asm volatile("s_waitcnt vmcnt(0)" ::: "memory");
        __builtin_amdgcn_sched_barrier(0);
        __builtin_amdgcn_s_barrier();
        __builtin_amdgcn_sched_barrier(0);

        if (kk < 14) stage((kk + 2) % 3, kk + 2);

        const int cb = kk % 3;
        bf16x8 af[4], bfr[4];
        #pragma unroll
        for (int f = 0; f < 4; ++f) {
            const int row = wr * 64 + f * 16 + l15;
            af[f] = *(const bf16x8*)&smem[cb][0][row * 32 + (l4 ^ ((row >> 1) & 3)) * 8];
        }
        #pragma unroll
        for (int gg = 0; gg < 4; ++gg) {
            const int row = wc * 64 + gg * 16 + l15;
            bfr[gg] = *(const bf16x8*)&smem[cb][1][row * 32 + (l4 ^ ((row >> 1) & 3)) * 8];
        }
        #pragma unroll
        for (int f = 0; f < 4; ++f)
            #pragma unroll
            for (int gg = 0; gg < 4; ++gg)
                acc[f][gg] = __builtin_amdgcn_mfma_f32_16x16x32_bf16(af[f], bfr[gg], acc[f][gg], 0, 0, 0);
    }
    __syncthreads();

    // transposed epilogue through LDS
    bf16_t* cst = &smem[0][0][0];               // 128x128 bf16 overlay
    const int sel = colt >> 2;                  // 0=Q, 1=K, 2=V
    const int nb  = nBase - sel * 512;
    const float* bp = (sel == 0) ? bq : ((sel == 1) ? bk : bv);

    if (sel < 2) {
        #pragma unroll
        for (int gg = 0; gg < 4; ++gg) {
            const int ncol = wc * 64 + gg * 16 + l15;
            const float bias_v = bp[nb + ncol];
            #pragma unroll
            for (int f = 0; f < 4; ++f)
                #pragma unroll
                for (int i = 0; i < 4; ++i)
                    cst[(wr * 64 + f * 16 + 4 * l4 + i) * 128 + ncol] = f2bf(acc[f][gg][i] + bias_v);
        }
        __syncthreads();
        bf16_t* Cout = (sel == 0) ? Q : K;
        #pragma unroll
        for (int rr = 0; rr < 4; ++rr) {
            const int r  = rr * 32 + (tid >> 3);
            const int c0 = (tid & 7) * 16;
            bf16x8 v0 = *(const bf16x8*)&cst[r * 128 + c0];
            bf16x8 v1 = *(const bf16x8*)&cst[r * 128 + c0 + 8];
            bf16_t* dst = Cout + (size_t)(mBase + r) * DIM + nb + c0;
            *(bf16x8*)dst       = v0;
            *(bf16x8*)(dst + 8) = v1;
        }
    } else {
        #pragma unroll
        for (int gg = 0; gg < 4; ++gg) {
            const int ncol = wc * 64 + gg * 16 + l15;
            const float bias_v = bp[nb + ncol];
            #pragma unroll
            for (int f = 0; f < 4; ++f) {
                bf16x4 pk;
                #pragma unroll
                for (int i = 0; i < 4; ++i) pk[i] = f2bf(acc[f][gg][i] + bias_v);
                *(bf16x4*)&cst[ncol * 128 + wr * 64 + f * 16 + 4 * l4] = pk;
            }
        }
        __syncthreads();
        #pragma unroll
        for (int rr = 0; rr < 4; ++rr) {
            const int nl = rr * 32 + (tid >> 3);
            const int m0 = (tid & 7) * 16;
            const int n  = nb + nl;
            const int mg0 = mBase + m0;
            const int bb0 = mg0 / TT, tt0 = mg0 - bb0 * TT;
            if (tt0 + 15 < TT) {
                bf16_t* dst = Vt + (size_t)bb0 * DIM * TKP + (size_t)n * TKP + tt0;
                #pragma unroll
                for (int u = 0; u < 4; ++u)
                    *(bf16x4*)(dst + u * 4) = *(const bf16x4*)&cst[nl * 128 + m0 + u * 4];
            } else {
                #pragma unroll
                for (int u = 0; u < 16; ++u) {
                    const int mg = mg0 + u;
                    const int bb = mg / TT, tt = mg - bb * TT;
                    Vt[(size_t)bb * DIM * TKP + (size_t)n * TKP + tt] = cst[nl * 128 + m0 + u];
                }
            }
        }
    }
}

// ---------------- merged attention: f2e blocks [0,512), e2f blocks [512,1152) --
// LDS overlay: f2e p[32][648]+m+l = 42.5 KB; e2f p[4][32][104] = 26.6 KB.
// Both halves: b = g&127 -> XCD = b%8 for every block of batch b (K/V L2-local).
__global__ __launch_bounds__(256, 3)
void attn_both(const bf16_t* __restrict__ Qe, const bf16_t* __restrict__ Kf,
               const bf16_t* __restrict__ VfT, float* __restrict__ OutF,
               const bf16_t* __restrict__ Qf, const bf16_t* __restrict__ Ke,
               const bf16_t* __restrict__ VeT, float* __restrict__ OutE)
{
    __shared__ __align__(16) char smem_raw[43520];

    const int gid = blockIdx.x;
    const int tid = threadIdx.x;
    const int wv = tid >> 6, lane = tid & 63, l15 = lane & 15, l4 = lane >> 4;

    if (gid < 512) {
        // ================= f2e: Q=fnirs 120 rows, K/V=eeg 600 keys =================
        bf16_t (*p_lds)[648] = (bf16_t(*)[648])smem_raw;                 // 41472 B
        float (*m_lds)[32]   = (float(*)[32])(smem_raw + 41472);         // 512 B
        float (*l_lds)[32]   = (float(*)[32])(smem_raw + 41984);         // 512 B

        const int b = gid & 127, qt = gid >> 7;
        const int qbase0 = qt * 32;
        const int koff = wv * 160;

        const bf16_t* Qb = Qf + (size_t)b * 120 * DIM;
        const bf16_t* Kb = Ke + (size_t)b * 600 * DIM;
        const bf16_t* Vb = VeT + (size_t)b * DIM * 608;

        const int qr0 = imin(qbase0 + l15, 119);
        const int qr1 = imin(qbase0 + 16 + l15, 119);
        const bf16_t* qp0 = Qb + (size_t)qr0 * DIM + l4 * 8;
        const bf16_t* qp1 = Qb + (size_t)qr1 * DIM + l4 * 8;

        int koffs[10];
        #pragma unroll
        for (int ch = 0; ch < 10; ++ch)
            koffs[ch] = imin(koff + ch * 16 + l15, 599) * (DIM * 2);
        const char* KbL = (const char*)(Kb + l4 * 8);

        f32x4 acc0[10], acc1[10];
        #pragma unroll
        for (int ch = 0; ch < 10; ++ch) { acc0[ch] = (f32x4){0.f,0.f,0.f,0.f};
                                          acc1[ch] = (f32x4){0.f,0.f,0.f,0.f}; }
        #pragma unroll 2
        for (int c = 0; c < 16; ++c) {
            bf16x8 q0c = *(const bf16x8*)(qp0 + c * 32);
            bf16x8 q1c = *(const bf16x8*)(qp1 + c * 32);
            #pragma unroll
            for (int ch = 0; ch < 10; ++ch) {
                bf16x8 kf = *(const bf16x8*)(KbL + koffs[ch] + c * 64);
                acc0[ch] = __builtin_amdgcn_mfma_f32_16x16x32_bf16(q0c, kf, acc0[ch], 0, 0, 0);
                acc1[ch] = __builtin_amdgcn_mfma_f32_16x16x32_bf16(q1c, kf, acc1[ch], 0, 0, 0);
            }
        }

        float m0[4] = {-INFINITY,-INFINITY,-INFINITY,-INFINITY};
        float m1[4] = {-INFINITY,-INFINITY,-INFINITY,-INFINITY};
        #pragma unroll
        for (int ch = 0; ch < 10; ++ch) {
            #pragma unroll
            for (int i = 0; i < 4; ++i) {
                const int k = koff + ch * 16 + l15;
                const int j0 = k / 20;
                {   const int j = qbase0 + 4 * l4 + i;
                    float s = (k >= 600) ? -INFINITY
                            : ((j >= j0 + 20 && j <= j0 + 80) ? acc0[ch][i] * SCALE : -1e9f);
                    acc0[ch][i] = s;  m0[i] = fmaxf(m0[i], s); }
                {   const int j = qbase0 + 16 + 4 * l4 + i;
                    float s = (k >= 600) ? -INFINITY
                            : ((j >= j0 + 20 && j <= j0 + 80) ? acc1[ch][i] * SCALE : -1e9f);
                    acc1[ch][i] = s;  m1[i] = fmaxf(m1[i], s); }
            }
        }
        #pragma unroll
        for (int i = 0; i < 4; ++i) {
            #pragma unroll
            for (int d = 1; d < 16; d <<= 1) {
                m0[i] = fmaxf(m0[i], __shfl_xor(m0[i], d, 16));
                m1[i] = fmaxf(m1[i], __shfl_xor(m1[i], d, 16));
            }
        }
        if (l15 == 0) {
            #pragma unroll
            for (int i = 0; i < 4; ++i) {
                m_lds[wv][4 * l4 + i]      = m0[i];
                m_lds[wv][16 + 4 * l4 + i] = m1[i];
            }
        }
        __syncthreads();
        float mg0[4], mg1[4];
        #pragma unroll
        for (int i = 0; i < 4; ++i) {
            const int r0 = 4 * l4 + i, r1 = 16 + 4 * l4 + i;
            mg0[i] = fmaxf(fmaxf(m_lds[0][r0], m_lds[1][r0]), fmaxf(m_lds[2][r0], m_lds[3][r0]));
            mg1[i] = fmaxf(fmaxf(m_lds[0][r1], m_lds[1][r1]), fmaxf(m_lds[2][r1], m_lds[3][r1]));
        }

        float l0[4] = {0.f,0.f,0.f,0.f}, l1[4] = {0.f,0.f,0.f,0.f};
        #pragma unroll
        for (int ch = 0; ch < 10; ++ch) {
            #pragma unroll
            for (int i = 0; i < 4; ++i) {
                float e0 = __expf(acc0[ch][i] - mg0[i]);
                float e1 = __expf(acc1[ch][i] - mg1[i]);
                l0[i] += e0;  l1[i] += e1;
                p_lds[4 * l4 + i][koff + ch * 16 + l15]      = f2bf(e0);
                p_lds[16 + 4 * l4 + i][koff + ch * 16 + l15] = f2bf(e1);
            }
        }
        #pragma unroll
        for (int i = 0; i < 4; ++i) {
            #pragma unroll
            for (int d = 1; d < 16; d <<= 1) {
                l0[i] += __shfl_xor(l0[i], d, 16);
                l1[i] += __shfl_xor(l1[i], d, 16);
            }
        }
        if (l15 == 0) {
            #pragma unroll
            for (int i = 0; i < 4; ++i) {
                l_lds[wv][4 * l4 + i]      = l0[i];
                l_lds[wv][16 + 4 * l4 + i] = l1[i];
            }
        }
        __syncthreads();   // P + l published

        float linv0[4], linv1[4];
        #pragma unroll
        for (int i = 0; i < 4; ++i) {
            const int r0 = 4 * l4 + i, r1 = 16 + 4 * l4 + i;
            linv0[i] = 1.0f / (l_lds[0][r0] + l_lds[1][r0] + l_lds[2][r0] + l_lds[3][r0]);
            linv1[i] = 1.0f / (l_lds[0][r1] + l_lds[1][r1] + l_lds[2][r1] + l_lds[3][r1]);
        }

        const int dbase = wv * 128;
        f32x4 o0[8], o1[8];
        #pragma unroll
        for (int u = 0; u < 8; ++u) { o0[u] = (f32x4){0.f,0.f,0.f,0.f};
                                      o1[u] = (f32x4){0.f,0.f,0.f,0.f}; }

        for (int kt = 0; kt < 20; ++kt) {
            bf16x8 pa0 = *(const bf16x8*)&p_lds[l15][kt * 32 + l4 * 8];
            bf16x8 pa1 = *(const bf16x8*)&p_lds[16 + l15][kt * 32 + l4 * 8];
            const int vcol = imin(kt * 32, 576);
            #pragma unroll
            for (int u = 0; u < 8; ++u) {
                bf16x8 vf = *(const bf16x8*)(Vb + (size_t)(dbase + u * 16 + l15) * 608 + vcol + l4 * 8);
                o0[u] = __builtin_amdgcn_mfma_f32_16x16x32_bf16(pa0, vf, o0[u], 0, 0, 0);
                o1[u] = __builtin_amdgcn_mfma_f32_16x16x32_bf16(pa1, vf, o1[u], 0, 0, 0);
            }
        }

        float* Ob = OutE + (size_t)b * 120 * DIM;
        #pragma unroll
        for (int u = 0; u < 8; ++u) {
            #pragma unroll
            for (int i = 0; i < 4; ++i) {
                const int col = dbase + u * 16 + l15;
                const int r0 = qbase0 + 4 * l4 + i;
                const int r1 = qbase0 + 16 + 4 * l4 + i;
                if (r0 < 120) Ob[(size_t)r0 * DIM + col] = o0[u][i] * linv0[i];
                if (r1 < 120) Ob[(size_t)r1 * DIM + col] = o1[u][i] * linv1[i];
            }
        }
    } else {
        // ================= e2f: Q=eeg 600 rows, K/V=fnirs 120 keys =================
        bf16_t (*p_lds)[32][104] = (bf16_t(*)[32][104])smem_raw;         // 26624 B

        const int g2 = gid - 512;
        const int b = g2 & 127, qb = g2 >> 7;
        const int qbase = qb * 128 + wv * 32;
        const int K0 = (((qbase / 20) + 20) >> 4) << 4;      // <= 48

        const bf16_t* Qb = Qe + (size_t)b * 600 * DIM;
        const bf16_t* Kb = Kf + (size_t)b * 120 * DIM;
        const bf16_t* Vb = VfT + (size_t)b * DIM * 128;

        const int qr0 = imin(qbase + l15, 599);
        const int qr1 = imin(qbase + 16 + l15, 599);
        const bf16_t* qp0 = Qb + (size_t)qr0 * DIM + l4 * 8;
        const bf16_t* qp1 = Qb + (size_t)qr1 * DIM + l4 * 8;

        int koffs[6];
        #pragma unroll
        for (int ch = 0; ch < 6; ++ch)
            koffs[ch] = imin(K0 + ch * 16 + l15, 119) * (DIM * 2);
        const char* KbL = (const char*)(Kb + l4 * 8);

        f32x4 acc0[6], acc1[6];
        #pragma unroll
        for (int ch = 0; ch < 6; ++ch) { acc0[ch] = (f32x4){0.f,0.f,0.f,0.f};
                                         acc1[ch] = (f32x4){0.f,0.f,0.f,0.f}; }
        #pragma unroll
        for (int c = 0; c < 16; ++c) {
            bf16x8 q0c = *(const bf16x8*)(qp0 + c * 32);
            bf16x8 q1c = *(const bf16x8*)(qp1 + c * 32);
            #pragma unroll
            for (int ch = 0; ch < 6; ++ch) {
                bf16x8 kf = *(const bf16x8*)(KbL + koffs[ch] + c * 64);
                acc0[ch] = __builtin_amdgcn_mfma_f32_16x16x32_bf16(q0c, kf, acc0[ch], 0, 0, 0);
                acc1[ch] = __builtin_amdgcn_mfma_f32_16x16x32_bf16(q1c, kf, acc1[ch], 0, 0, 0);
            }
        }

        float m0[4] = {-INFINITY,-INFINITY,-INFINITY,-INFINITY};
        float m1[4] = {-INFINITY,-INFINITY,-INFINITY,-INFINITY};
        #pragma unroll
        for (int ch = 0; ch < 6; ++ch) {
            #pragma unroll
            for (int i = 0; i < 4; ++i) {
                const int k = K0 + ch * 16 + l15;
                {   const int t = qbase + 4 * l4 + i;
                    const int j0 = t / 20;
                    const bool v = (k < 120) && (k >= j0 + 20) && (k <= j0 + 80);
                    float s = v ? acc0[ch][i] * SCALE : -INFINITY;
                    acc0[ch][i] = s;  m0[i] = fmaxf(m0[i], s); }
                {   const int t = qbase + 16 + 4 * l4 + i;
                    const int j0 = t / 20;
                    const bool v = (k < 120) && (k >= j0 + 20) && (k <= j0 + 80);
                    float s = v ? acc1[ch][i] * SCALE : -INFINITY;
                    acc1[ch][i] = s;  m1[i] = fmaxf(m1[i], s); }
            }
        }
        #pragma unroll
        for (int i = 0; i < 4; ++i) {
            #pragma unroll
            for (int d = 1; d < 16; d <<= 1) {
                m0[i] = fmaxf(m0[i], __shfl_xor(m0[i], d, 16));
                m1[i] = fmaxf(m1[i], __shfl_xor(m1[i], d, 16));
            }
        }

        float l0[4] = {0.f,0.f,0.f,0.f}, l1[4] = {0.f,0.f,0.f,0.f};
        #pragma unroll
        for (int ch = 0; ch < 6; ++ch) {
            #pragma unroll
            for (int i = 0; i < 4; ++i) {
                float e0 = __expf(acc0[ch][i] - m0[i]);
                float e1 = __expf(acc1[ch][i] - m1[i]);
                l0[i] += e0;  l1[i] += e1;
                p_lds[wv][4 * l4 + i][ch * 16 + l15]      = f2bf(e0);
                p_lds[wv][16 + 4 * l4 + i][ch * 16 + l15] = f2bf(e1);
            }
        }
        #pragma unroll
        for (int i = 0; i < 4; ++i) {
            #pragma unroll
            for (int d = 1; d < 16; d <<= 1) {
                l0[i] += __shfl_xor(l0[i], d, 16);
                l1[i] += __shfl_xor(l1[i], d, 16);
            }
            l0[i] = 1.0f / l0[i];
            l1[i] = 1.0f / l1[i];
        }
        __syncthreads();   // fence p_lds write -> read

        bf16x8 pa0[3], pa1[3];
        #pragma unroll
        for (int kt = 0; kt < 3; ++kt) {
            pa0[kt] = *(const bf16x8*)&p_lds[wv][l15][kt * 32 + l4 * 8];
            pa1[kt] = *(const bf16x8*)&p_lds[wv][16 + l15][kt * 32 + l4 * 8];
        }
        int vb[3];
        #pragma unroll
        for (int kt = 0; kt < 3; ++kt) vb[kt] = imin(K0 + kt * 32, 96);  // P==0 where clamped

        float* Ob = OutF + (size_t)b * 600 * DIM;
        #pragma unroll
        for (int dcg = 0; dcg < 8; ++dcg) {
            f32x4 o0[4], o1[4];
            #pragma unroll
            for (int u = 0; u < 4; ++u) { o0[u] = (f32x4){0.f,0.f,0.f,0.f};
                                          o1[u] = (f32x4){0.f,0.f,0.f,0.f}; }
            #pragma unroll
            for (int u = 0; u < 4; ++u) {
                const bf16_t* vrow = Vb + (size_t)(dcg * 64 + u * 16 + l15) * 128 + l4 * 8;
                #pragma unroll
                for (int kt = 0; kt < 3; ++kt) {
                    bf16x8 vf = *(const bf16x8*)(vrow + vb[kt]);
                    o0[u] = __builtin_amdgcn_mfma_f32_16x16x32_bf16(pa0[kt], vf, o0[u], 0, 0, 0);
                    o1[u] = __builtin_amdgcn_mfma_f32_16x16x32_bf16(pa1[kt], vf, o1[u], 0, 0, 0);
                }
            }
            #pragma unroll
            for (int u = 0; u < 4; ++u) {
                #pragma unroll
                for (int i = 0; i < 4; ++i) {
                    const int col = (dcg * 4 + u) * 16 + l15;
                    const int t0 = qbase + 4 * l4 + i;
                    const int t1 = qbase + 16 + 4 * l4 + i;
                    if (t0 < 600) Ob[(size_t)t0 * DIM + col] = o0[u][i] * l0[i];
                    if (t1 < 600) Ob[(size_t)t1 * DIM + col] = o1[u][i] * l1[i];
                }
            }
        }
    }
}

// ---------------- host launch ----------------
extern "C" void kernel_launch(void* const* d_in, const int* in_sizes, int n_in,
                              void* d_out, int out_size, void* d_ws, size_t ws_size,
                              hipStream_t stream)
{
    (void)in_sizes; (void)n_in; (void)out_size; (void)ws_size;
    const float* eeg   = (const float*)d_in[0];
    const float* fnirs = (const float*)d_in[1];
    const float* Wqe = (const float*)d_in[2];  const float* bqe = (const float*)d_in[3];
    const float* Wke = (const float*)d_in[4];  const float* bke = (const float*)d_in[5];
    const float* Wve = (const float*)d_in[6];  const float* bve = (const float*)d_in[7];
    const float* Wqf = (const float*)d_in[8];  const float* bqf = (const float*)d_in[9];
    const float* Wkf = (const float*)d_in[10]; const float* bkf = (const float*)d_in[11];
    const float* Wvf = (const float*)d_in[12]; const float* bvf = (const float*)d_in[13];

    char* ws = (char*)d_ws;
    bf16_t* Wt   = (bf16_t*)(ws);                      // 3,145,728 B
    bf16_t* Qe   = (bf16_t*)(ws + 3145728);            // 78,643,200
    bf16_t* Ke   = (bf16_t*)(ws + 81788928);           // 78,643,200
    bf16_t* Qf   = (bf16_t*)(ws + 160432128);          // 15,728,640
    bf16_t* Kf   = (bf16_t*)(ws + 176160768);          // 15,728,640
    bf16_t* Ve_t = (bf16_t*)(ws + 191889408);          // 79,691,776
    bf16_t* Vf_t = (bf16_t*)(ws + 271581184);          // 16,777,216  (total 288,358,400)

    float* out_eeg   = (float*)d_out;                              // [128][120][512]
    float* out_fnirs = (float*)d_out + (size_t)128 * 120 * 512;    // [128][600][512]

    // bf16 copies of the activations, parked in d_out (fully overwritten by attn later)
    bf16_t* eeg_bf   = (bf16_t*)out_fnirs;     // 78.6 MB <= 157 MB region
    bf16_t* fnirs_bf = (bf16_t*)out_eeg;       // 15.7 MB <= 31.5 MB region

    const int n8_e = 128 * 600 * DIM / 8;      // 4,915,200
    const int n8_f = 128 * 120 * DIM / 8;      // 983,040
    const int nCast = (n8_e + n8_f + 255) / 256;   // 23040

    // cast + weight-transpose fused (23040 cast blocks + 1536 wt blocks)
    cast_wt<<<nCast + 1536, 256, 0, stream>>>(eeg, eeg_bf, n8_e,
                                              fnirs, fnirs_bf, n8_f, nCast,
                                              Wqe, Wke, Wve, Wqf, Wkf, Wvf, Wt);

    // fused QKV projections, both sides in one dispatch (7200 eeg + 1440 fnirs)
    proj_both<<<8640, 256, 0, stream>>>(eeg_bf, fnirs_bf, Wt,
                                        bqe, bke, bve, bqf, bkf, bvf,
                                        Qe, Ke, Ve_t, Qf, Kf, Vf_t);

    // both attentions in one dispatch (512 f2e + 640 e2f)
    attn_both<<<1152, 256, 0, stream>>>(Qe, Kf, Vf_t, out_fnirs,
                                        Qf, Ke, Ve_t, out_eeg);
}